// Round 1
// baseline (219.154 us; speedup 1.0000x reference)
//
#include <hip/hip_runtime.h>
#include <stdint.h>

// Problem: x (32,128,8192) f32, weight (128,128,1,2) f32
// out[b,o,p] = sum_{c,k} x[b,c,2p+k] * w[o,c,k] / sqrt(128),  out (32,128,4096) f32
// GEMM: M=(b,p)=131072, N=o=128, K=(c,k)=256. Memory-bound with bf16 MFMA.

typedef __attribute__((ext_vector_type(8))) short bf16x8;   // 8 bf16 = 4 VGPRs
typedef __attribute__((ext_vector_type(4))) float f32x4;    // MFMA C/D

#define CIN  128
#define DLEN 8192
#define PLEN 4096
#define COUT 128

__device__ inline unsigned short f2bf(float f) {
    // round-to-nearest-even fp32 -> bf16 (inputs are finite normals)
    unsigned u = __builtin_bit_cast(unsigned, f);
    unsigned r = u + 0x7FFFu + ((u >> 16) & 1u);
    return (unsigned short)(r >> 16);
}

// Convert weight (o,c,1,k) f32 -> bf16 in B-fragment-major layout, scale folded in.
// W flat index = o*256 + (c*2+k) = o*256 + kk.  WB bf16 index = (kk>>3)*1024 + o*8 + (kk&7).
__global__ __launch_bounds__(256) void convert_w(const float* __restrict__ w,
                                                 unsigned short* __restrict__ wb) {
    int t  = blockIdx.x * 256 + threadIdx.x;   // 0..16383
    int o  = t >> 7;                           // 0..127
    int k0 = (t & 127) * 2;                    // even k index 0..254
    const float scale = 0.088388347648318447f; // 1/sqrt(128)
    float2 f = *(const float2*)(w + o * 256 + k0);
    unsigned v = (unsigned)f2bf(f.x * scale) | ((unsigned)f2bf(f.y * scale) << 16);
    int idx = (k0 >> 3) * 1024 + o * 8 + (k0 & 7);      // even -> dword aligned
    *(unsigned*)(wb + idx) = v;
}

// One block = 4 waves = 256 threads. Block covers 128 positions of one batch,
// all 128 outputs, K=256. Wave w: 32 positions (two 16x16 M-tiles).
// No LDS, no barriers: A straight from HBM (each element read exactly once),
// B fragments from L2-resident preconverted workspace.
__global__ __launch_bounds__(256, 3) void conv_mfma(const float* __restrict__ x,
                                                    const unsigned short* __restrict__ wb,
                                                    float* __restrict__ out) {
    int tile = blockIdx.x;            // 0..1023
    int b    = tile >> 5;             // 32 tiles per batch
    int pt   = (tile & 31) * 128;     // position tile base
    int lane = threadIdx.x & 63;
    int w    = threadIdx.x >> 6;      // wave 0..3
    int quad = lane >> 4;
    int l16  = lane & 15;

    const float* xb = x + (size_t)b * ((size_t)CIN * DLEN);
    int p0 = pt + w * 32 + l16;       // mt=0 position for this lane

    f32x4 acc[2][8];
#pragma unroll
    for (int mt = 0; mt < 2; ++mt)
#pragma unroll
        for (int t = 0; t < 8; ++t)
            acc[mt][t] = (f32x4)(0.0f);

    const uint32_t* wb32 = (const uint32_t*)wb;

#pragma unroll 1
    for (int kc = 0; kc < 8; ++kc) {
        // ---- A: lane needs k = kc*32 + quad*8 + j (j=0..7) for m and m+16.
        // k = 2c+kk  ->  c = kc*16 + quad*4 + jj, kk in {0,1}: 4 rows x float2 each.
        int cbase = kc * 16 + quad * 4;
        float2 af0[4], af1[4];
#pragma unroll
        for (int jj = 0; jj < 4; ++jj) {
            const float* rowp = xb + (size_t)(cbase + jj) * DLEN + 2 * p0;
            af0[jj] = *(const float2*)(rowp);        // position p0
            af1[jj] = *(const float2*)(rowp + 32);   // position p0+16
        }
        union { bf16x8 v; unsigned uu[4]; } afr0, afr1;
#pragma unroll
        for (int jj = 0; jj < 4; ++jj) {
            afr0.uu[jj] = (unsigned)f2bf(af0[jj].x) | ((unsigned)f2bf(af0[jj].y) << 16);
            afr1.uu[jj] = (unsigned)f2bf(af1[jj].x) | ((unsigned)f2bf(af1[jj].y) << 16);
        }

        // ---- B fragments: 16B per (n-tile); k-group = kc*4+quad, n = t*16+l16.
        const uint32_t* bbase = wb32 + (size_t)(kc * 4 + quad) * 512 + l16 * 4;
#pragma unroll
        for (int t = 0; t < 8; ++t) {
            union { bf16x8 v; uint4 u; } bf_;
            bf_.u = *(const uint4*)(bbase + t * 64);
            acc[0][t] = __builtin_amdgcn_mfma_f32_16x16x32_bf16(afr0.v, bf_.v, acc[0][t], 0, 0, 0);
            acc[1][t] = __builtin_amdgcn_mfma_f32_16x16x32_bf16(afr1.v, bf_.v, acc[1][t], 0, 0, 0);
        }
    }

    // ---- Epilogue: C/D reg r -> row quad*4+r -> consecutive p => float4 stores.
    float* ob = out + (size_t)b * ((size_t)COUT * PLEN);
#pragma unroll
    for (int t = 0; t < 8; ++t) {
        int o = t * 16 + l16;
        float* orow = ob + (size_t)o * PLEN + pt + w * 32 + quad * 4;
        *(f32x4*)(orow)      = acc[0][t];
        *(f32x4*)(orow + 16) = acc[1][t];
    }
}

extern "C" void kernel_launch(void* const* d_in, const int* in_sizes, int n_in,
                              void* d_out, int out_size, void* d_ws, size_t ws_size,
                              hipStream_t stream) {
    const float* x = (const float*)d_in[0];
    const float* w = (const float*)d_in[1];
    float* out = (float*)d_out;
    unsigned short* wb = (unsigned short*)d_ws;  // 64 KB of bf16 weights

    convert_w<<<64, 256, 0, stream>>>(w, wb);
    conv_mfma<<<1024, 256, 0, stream>>>(x, wb, out);
}

// Round 2
// 212.725 us; speedup vs baseline: 1.0302x; 1.0302x over previous
//
#include <hip/hip_runtime.h>
#include <stdint.h>

// Problem: x (32,128,8192) f32, weight (128,128,1,2) f32
// out[b,o,p] = sum_{c,k} x[b,c,2p+k] * w[o,c,k] / sqrt(128),  out (32,128,4096) f32
// GEMM: M=(b,p)=131072, N=o=128, K=(c,k)=256. Memory-bound with bf16 MFMA.
//
// R2: latency-bound fix — position-interleaved M-tiles so A loads are dwordx4
// (one float4 feeds both tiles), prefetch-distance-1 on A, B single-buffered
// in 2 batches, __launch_bounds__(256,4) for full 4-waves/SIMD residency.

typedef __attribute__((ext_vector_type(8))) short bf16x8;   // 8 bf16 = 4 VGPRs
typedef __attribute__((ext_vector_type(4))) float f32x4;    // MFMA C/D

#define CIN  128
#define DLEN 8192
#define PLEN 4096
#define COUT 128

__device__ inline unsigned short f2bf(float f) {
    unsigned u = __builtin_bit_cast(unsigned, f);
    unsigned r = u + 0x7FFFu + ((u >> 16) & 1u);
    return (unsigned short)(r >> 16);
}

// pack two fp32 -> bf16x2 (RTNE), lo = a, hi = b
__device__ inline unsigned pack_bf(float a, float b) {
    unsigned ua = __builtin_bit_cast(unsigned, a);
    unsigned ub = __builtin_bit_cast(unsigned, b);
    unsigned ra = ua + 0x7FFFu + ((ua >> 16) & 1u);
    unsigned rb = ub + 0x7FFFu + ((ub >> 16) & 1u);
    return (ra >> 16) | (rb & 0xFFFF0000u);
}

// Convert weight (o,c,1,k) f32 -> bf16 in B-fragment-major layout, scale folded in.
// W flat index = o*256 + (c*2+k) = o*256 + kk.  WB bf16 index = (kk>>3)*1024 + o*8 + (kk&7).
__global__ __launch_bounds__(256) void convert_w(const float* __restrict__ w,
                                                 unsigned short* __restrict__ wb) {
    int t  = blockIdx.x * 256 + threadIdx.x;   // 0..16383
    int o  = t >> 7;                           // 0..127
    int k0 = (t & 127) * 2;                    // even k index 0..254
    const float scale = 0.088388347648318447f; // 1/sqrt(128)
    float2 f = *(const float2*)(w + o * 256 + k0);
    unsigned v = (unsigned)f2bf(f.x * scale) | ((unsigned)f2bf(f.y * scale) << 16);
    int idx = (k0 >> 3) * 1024 + o * 8 + (k0 & 7);
    *(unsigned*)(wb + idx) = v;
}

// One block = 4 waves = 256 threads, covers 128 positions of one batch, all 128
// outputs, K=256. Each wave: 32 consecutive positions, interleaved across two
// 16x16 M-tiles (tile0 = even offsets, tile1 = odd), so each A row load is one
// float4 covering both tiles. No LDS, no barriers.
__global__ __launch_bounds__(256, 4) void conv_mfma(const float* __restrict__ x,
                                                    const unsigned short* __restrict__ wb,
                                                    float* __restrict__ out) {
    int tile = blockIdx.x;            // 0..1023
    int b    = tile >> 5;
    int pt   = (tile & 31) * 128;
    int lane = threadIdx.x & 63;
    int w    = threadIdx.x >> 6;      // wave 0..3
    int quad = lane >> 4;
    int l16  = lane & 15;
    int pbase = pt + w * 32;          // wave's 32-position strip

    // A lane base: row c = quad*4 (+jj, +16*kc), elem 2*pbase + 4*l16
    const float* xl = x + (size_t)b * ((size_t)CIN * DLEN)
                        + (size_t)(quad * 4) * DLEN + 2 * pbase + 4 * l16;
    const uint32_t* bb = (const uint32_t*)wb + quad * 512 + l16 * 4;

    f32x4 acc[2][8];
#pragma unroll
    for (int mt = 0; mt < 2; ++mt)
#pragma unroll
        for (int t = 0; t < 8; ++t)
            acc[mt][t] = (f32x4)(0.0f);

    // preload kc=0 A
    float4 abuf[4];
#pragma unroll
    for (int jj = 0; jj < 4; ++jj)
        abuf[jj] = *(const float4*)(xl + (size_t)jj * DLEN);

#pragma unroll 1
    for (int kc = 0; kc < 8; ++kc) {
        // consume current A: .x/.y -> tile0 (even pos), .z/.w -> tile1 (odd pos)
        union { bf16x8 v; unsigned uu[4]; } afr0, afr1;
#pragma unroll
        for (int jj = 0; jj < 4; ++jj) {
            afr0.uu[jj] = pack_bf(abuf[jj].x, abuf[jj].y);
            afr1.uu[jj] = pack_bf(abuf[jj].z, abuf[jj].w);
        }
        // prefetch next kc A (distance 1, same regs — abuf already consumed)
        if (kc < 7) {
            const float* nx = xl + (size_t)((kc + 1) * 16) * DLEN;
#pragma unroll
            for (int jj = 0; jj < 4; ++jj)
                abuf[jj] = *(const float4*)(nx + (size_t)jj * DLEN);
        }
        // B fragments for this kc: kgroup = kc*4+quad, t-stride 64 dwords
        const uint32_t* bk = bb + kc * 2048;
#pragma unroll
        for (int th = 0; th < 2; ++th) {
            union { bf16x8 v; uint4 u; } bfr[4];
#pragma unroll
            for (int tt = 0; tt < 4; ++tt)
                bfr[tt].u = *(const uint4*)(bk + (th * 4 + tt) * 64);
#pragma unroll
            for (int tt = 0; tt < 4; ++tt) {
                int t = th * 4 + tt;
                acc[0][t] = __builtin_amdgcn_mfma_f32_16x16x32_bf16(afr0.v, bfr[tt].v, acc[0][t], 0, 0, 0);
                acc[1][t] = __builtin_amdgcn_mfma_f32_16x16x32_bf16(afr1.v, bfr[tt].v, acc[1][t], 0, 0, 0);
            }
        }
    }

    // Epilogue: C/D row = quad*4 + reg. tile0 reg r -> p = pbase+8q+2r,
    // tile1 -> +1. Interleave regs -> 8 consecutive positions per t.
    float* ob = out + (size_t)b * ((size_t)COUT * PLEN) + pbase + quad * 8;
#pragma unroll
    for (int t = 0; t < 8; ++t) {
        int o = t * 16 + l16;
        float* orow = ob + (size_t)o * PLEN;
        f32x4 v0 = { acc[0][t][0], acc[1][t][0], acc[0][t][1], acc[1][t][1] };
        f32x4 v1 = { acc[0][t][2], acc[1][t][2], acc[0][t][3], acc[1][t][3] };
        *(f32x4*)(orow)     = v0;
        *(f32x4*)(orow + 4) = v1;
    }
}

extern "C" void kernel_launch(void* const* d_in, const int* in_sizes, int n_in,
                              void* d_out, int out_size, void* d_ws, size_t ws_size,
                              hipStream_t stream) {
    const float* x = (const float*)d_in[0];
    const float* w = (const float*)d_in[1];
    float* out = (float*)d_out;
    unsigned short* wb = (unsigned short*)d_ws;  // 64 KB of bf16 weights

    convert_w<<<64, 256, 0, stream>>>(w, wb);
    conv_mfma<<<1024, 256, 0, stream>>>(x, wb, out);
}